// Round 2
// baseline (24916.731 us; speedup 1.0000x reference)
//
#include <hip/hip_runtime.h>

#define T_LEN 1024
#define B_N   64
#define D_N   256
#define Q_N   128
#define NCOL  2816      // 256 w | 256 pu | 256 pv | 1024 gi | 1024 gh
#define G1_N  1792
#define NT    256

typedef __attribute__((ext_vector_type(8))) short short8;
typedef __attribute__((ext_vector_type(4))) float floatx4;

#define MFMA16(A, B, C) __builtin_amdgcn_mfma_f32_16x16x32_bf16((A), (B), (C), 0, 0, 0)

__device__ __forceinline__ float fsigmoid(float x) { return 1.f / (1.f + __expf(-x)); }
__device__ __forceinline__ float ftanh(float x) {
  float ax = fabsf(x);
  float e = __expf(-2.f * ax);
  float r = (1.f - e) / (1.f + e);
  return (x < 0.f) ? -r : r;
}

// 3-term truncation split: x = h + m + l + eps, |eps| <~ 2^-24 |x|
struct Split3 { short8 h, m, l; };
__device__ __forceinline__ Split3 split8(const float* x) {
  union U { unsigned u[4]; short8 s; } H, M, L;
#pragma unroll
  for (int i = 0; i < 4; ++i) {
    float x0 = x[2 * i], x1 = x[2 * i + 1];
    unsigned h0 = __float_as_uint(x0) & 0xffff0000u;
    unsigned h1 = __float_as_uint(x1) & 0xffff0000u;
    float r0 = x0 - __uint_as_float(h0);
    float r1 = x1 - __uint_as_float(h1);
    unsigned m0 = __float_as_uint(r0) & 0xffff0000u;
    unsigned m1 = __float_as_uint(r1) & 0xffff0000u;
    float s0 = r0 - __uint_as_float(m0);
    float s1 = r1 - __uint_as_float(m1);
    H.u[i] = (h0 >> 16) | h1;
    M.u[i] = (m0 >> 16) | m1;
    L.u[i] = (__float_as_uint(s0) >> 16) | (__float_as_uint(s1) & 0xffff0000u);
  }
  Split3 r; r.h = H.s; r.m = M.s; r.l = L.s; return r;
}

// 6-product split-bf16 "fp32" MFMA: keeps hh, hm, mh, mm, hl, lh
__device__ __forceinline__ floatx4 mfma6(floatx4 acc, const Split3& A,
                                         short8 Bh, short8 Bm, short8 Bl) {
  acc = MFMA16(A.l, Bh, acc);
  acc = MFMA16(A.h, Bl, acc);
  acc = MFMA16(A.m, Bm, acc);
  acc = MFMA16(A.m, Bh, acc);
  acc = MFMA16(A.h, Bm, acc);
  acc = MFMA16(A.h, Bh, acc);
  return acc;
}

// ---------------- prep: W -> 3-way bf16 split Wcat[n][k]; vstate=v0; flags=0 --
__global__ void prep_kernel(const float* __restrict__ Wpu, const float* __restrict__ Wqu,
                            const float* __restrict__ Wpv, const float* __restrict__ Wih,
                            const float* __restrict__ Whh, const float* __restrict__ v0,
                            unsigned short* __restrict__ Wh, unsigned short* __restrict__ Wm,
                            unsigned short* __restrict__ Wl,
                            float* __restrict__ vstate, unsigned* __restrict__ flags) {
  int idx = blockIdx.x * 256 + threadIdx.x;
  const int total = NCOL * 256;                 // 720896
  if (idx < total) {
    int n = idx >> 8, k = idx & 255;
    float w;
    if      (n < 256)  w = Wqu[k * 256 + n];            // w-col:  sum_k v[k] Wqu[k][n]
    else if (n < 512)  w = Wpu[k * 256 + (n - 256)];    // pu-col: sum_k v[k] Wpu[k][e]
    else if (n < 768)  w = Wpv[k * 256 + (n - 512)];    // pv-col
    else if (n < 1792) w = Wih[(n - 768) * 256 + k];    // gi: sum_k v[k] Wih[j][k]
    else               w = Whh[(n - 1792) * 256 + k];   // gh: sum_k ut[k] Whh[j][k]
    unsigned hb = __float_as_uint(w) & 0xffff0000u;
    float r1 = w - __uint_as_float(hb);
    unsigned mb = __float_as_uint(r1) & 0xffff0000u;
    float r2 = r1 - __uint_as_float(mb);
    Wh[idx] = (unsigned short)(hb >> 16);
    Wm[idx] = (unsigned short)(mb >> 16);
    Wl[idx] = (unsigned short)(__float_as_uint(r2) >> 16);
  } else if (idx < total + B_N * 256) {
    int i = idx - total;
    vstate[i] = v0[i];
  } else if (idx < total + B_N * 256 + 128) {
    flags[idx - total - B_N * 256] = 0u;
  }
}

// ---------------- group sync helpers (16 members per group) ------------------
__device__ __forceinline__ void wait_flags(const unsigned* f, unsigned val) {
  if (threadIdx.x < 64) {
    const unsigned* fp = f + (threadIdx.x & 15);
    unsigned v;
    do {
      __builtin_amdgcn_s_sleep(1);
      v = __hip_atomic_load(fp, __ATOMIC_RELAXED, __HIP_MEMORY_SCOPE_AGENT);
    } while (__any((int)(v < val)));
  }
  if (threadIdx.x == 0) __builtin_amdgcn_fence(__ATOMIC_ACQUIRE, "agent");
  __syncthreads();
}
__device__ __forceinline__ void signal_flag(unsigned* f, unsigned val) {
  __syncthreads();                 // drains each wave's stores (vmcnt 0) before barrier
  if (threadIdx.x == 0) {
    __builtin_amdgcn_fence(__ATOMIC_RELEASE, "agent");
    __hip_atomic_store(f, val, __ATOMIC_RELAXED, __HIP_MEMORY_SCOPE_AGENT);
  }
}

// ---------------- main: 64 WGs x 256 thr; 4 groups x 16 WGs; b = g*16+m ------
__launch_bounds__(NT, 1)
__global__ void pq_main(const float* __restrict__ p, const float* __restrict__ q,
                        const float* __restrict__ bih, const float* __restrict__ bhh,
                        const unsigned short* __restrict__ Wh,
                        const unsigned short* __restrict__ Wm,
                        const unsigned short* __restrict__ Wl,
                        float* __restrict__ G, float* __restrict__ vstate,
                        unsigned* __restrict__ flagsA, unsigned* __restrict__ flagsB,
                        float* __restrict__ out) {
  extern __shared__ float smem[];
  float* lds_q = smem;             // 128 x 256 fp32, xor-swizzled chunks (131072 B)
  float* lds_v = smem + 32768;     // 16 x 264 fp32 (pad kills MFMA-read conflicts)
  float* grow  = smem + 36992;     // 2816 fp32: my G row
  float* spart = smem + 39808;     // 256
  float* bpart = smem + 40064;     // 256
  float* srow  = smem + 40320;     // 128
  float* scal  = smem + 40448;     // beta, 1/r

  const int tid  = threadIdx.x;
  const int g    = blockIdx.x >> 4;
  const int m    = blockIdx.x & 15;
  const int b    = g * 16 + m;
  const int lane = tid & 63;
  const int widx = tid >> 6;             // wave 0..3
  const int gw   = m * 4 + widx;         // group-wave 0..63
  const int n0_1 = gw * 28;              // G1: 28 cols (16 + 12)
  const int n0_2 = G1_N + gw * 16;       // G2: 16 cols
  const int row  = lane & 15;
  const int kb   = lane >> 4;

  // ---- one-time: stage my batch's q (fp32, swizzled), bias regs ----
  for (int i = 0; i < Q_N; ++i) {
    float val = q[((size_t)i * B_N + b) * D_N + tid];
    int cc = (tid >> 2) ^ (i & 7);
    lds_q[i * 256 + cc * 4 + (tid & 3)] = val;
  }
  const float bI = bih[tid]       + bhh[tid];
  const float bF = bih[256 + tid] + bhh[256 + tid];
  const float bG = bih[512 + tid] + bhh[512 + tid];
  const float bO = bih[768 + tid] + bhh[768 + tid];
  __syncthreads();

  // ---- register-resident B fragments: 3 tiles x 3 splits x 8 k-steps ----
  short8 Bh1a[8], Bm1a[8], Bl1a[8], Bh1b[8], Bm1b[8], Bl1b[8], Bh2[8], Bm2[8], Bl2[8];
#pragma unroll
  for (int ks = 0; ks < 8; ++ks) {
    int ko  = ks * 32 + kb * 8;
    int c1a = (n0_1 + row) * 256 + ko;
    int c1b = (n0_1 + 16 + row) * 256 + ko;
    int c2  = (n0_2 + row) * 256 + ko;
    Bh1a[ks] = *(const short8*)&Wh[c1a]; Bm1a[ks] = *(const short8*)&Wm[c1a]; Bl1a[ks] = *(const short8*)&Wl[c1a];
    Bh1b[ks] = *(const short8*)&Wh[c1b]; Bm1b[ks] = *(const short8*)&Wm[c1b]; Bl1b[ks] = *(const short8*)&Wl[c1b];
    Bh2[ks]  = *(const short8*)&Wh[c2];  Bm2[ks]  = *(const short8*)&Wm[c2];  Bl2[ks]  = *(const short8*)&Wl[c2];
  }

  float hout = 0.f;

  for (int t = 0; t < T_LEN; ++t) {
    // ---- G2 = ut @ Whh^T slice: depends only on p[t]; runs before the v-wait ----
    floatx4 acc2 = {0.f, 0.f, 0.f, 0.f};
    const float* pb = p + ((size_t)t * B_N + g * 16) * D_N;
#pragma unroll
    for (int ks = 0; ks < 8; ++ks) {
      float xa[8];
      const float* pr = pb + row * D_N + ks * 32 + kb * 8;
      *(float4*)&xa[0] = *(const float4*)pr;
      *(float4*)&xa[4] = *(const float4*)(pr + 4);
      Split3 A = split8(xa);
      acc2 = mfma6(acc2, A, Bh2[ks], Bm2[ks], Bl2[ks]);
    }

    // ---- wait v_t ready; stage the group's 16 v rows into LDS ----
    wait_flags(flagsB + g * 16, (unsigned)t);
    for (int i = 0; i < 16; ++i) {
      float v = __hip_atomic_load(&vstate[(g * 16 + i) * 256 + tid],
                                  __ATOMIC_RELAXED, __HIP_MEMORY_SCOPE_AGENT);
      lds_v[i * 264 + tid] = v;
    }
    __syncthreads();

    // ---- G1 = v @ [Wqu|Wpu^T|Wpv^T|Wih^T] slice ----
    floatx4 acc1a = {0.f, 0.f, 0.f, 0.f}, acc1b = {0.f, 0.f, 0.f, 0.f};
#pragma unroll
    for (int ks = 0; ks < 8; ++ks) {
      float xa[8];
      const float* vr = &lds_v[row * 264 + ks * 32 + kb * 8];
      *(float4*)&xa[0] = *(const float4*)vr;
      *(float4*)&xa[4] = *(const float4*)(vr + 4);
      Split3 A = split8(xa);
      acc1a = mfma6(acc1a, A, Bh1a[ks], Bm1a[ks], Bl1a[ks]);
      acc1b = mfma6(acc1b, A, Bh1b[ks], Bm1b[ks], Bl1b[ks]);
    }

    // ---- store G slice (C/D: col=lane&15, row=(lane>>4)*4+r), signal A ----
    {
      int col = lane & 15, r0 = (lane >> 4) * 4;
#pragma unroll
      for (int r = 0; r < 4; ++r) {
        size_t brow = (size_t)(g * 16 + r0 + r) * NCOL;
        __hip_atomic_store(&G[brow + n0_1 + col], acc1a[r], __ATOMIC_RELAXED, __HIP_MEMORY_SCOPE_AGENT);
        if (col < 12)
          __hip_atomic_store(&G[brow + n0_1 + 16 + col], acc1b[r], __ATOMIC_RELAXED, __HIP_MEMORY_SCOPE_AGENT);
        __hip_atomic_store(&G[brow + n0_2 + col], acc2[r], __ATOMIC_RELAXED, __HIP_MEMORY_SCOPE_AGENT);
      }
    }
    signal_flag(&flagsA[g * 16 + m], (unsigned)(t + 1));

    // ---- phase 2 (each WG owns batch b): wait all G slices, read my row ----
    wait_flags(flagsA + g * 16, (unsigned)(t + 1));
    for (int i = 0; i < 11; ++i) {
      int n = i * 256 + tid;
      if (n < NCOL)
        grow[n] = __hip_atomic_load(&G[(size_t)b * NCOL + n],
                                    __ATOMIC_RELAXED, __HIP_MEMORY_SCOPE_AGENT);
    }
    __syncthreads();

    // beta = pu.ut + pv.v
    float utd = p[((size_t)t * B_N + b) * D_N + tid];
    bpart[tid] = grow[256 + tid] * utd + grow[512 + tid] * lds_v[m * 264 + tid];
    __syncthreads();
    if (tid < 64) {
      float s = bpart[tid] + bpart[tid + 64] + bpart[tid + 128] + bpart[tid + 192];
#pragma unroll
      for (int off = 1; off < 64; off <<= 1) s += __shfl_xor(s, off);
      if (tid == 0) scal[0] = s;
    }
    // term1[q] = q[q,:].w  (swizzle-consistent fp32 dot)
    {
      int qq = tid >> 1, half = tid & 1, k = qq & 7;
      const float4* qrow = (const float4*)&lds_q[qq * 256 + half * 128];
      const float4* wrow = (const float4*)&grow[half * 128];
      float acc = 0.f;
#pragma unroll 8
      for (int i = 0; i < 32; ++i) {
        float4 qv = qrow[i];
        float4 wv = wrow[i ^ k];
        acc += qv.x * wv.x + qv.y * wv.y + qv.z * wv.z + qv.w * wv.w;
      }
      spart[tid] = acc;
    }
    __syncthreads();
    if (tid < Q_N) srow[tid] = spart[2 * tid] + spart[2 * tid + 1] + scal[0];
    __syncthreads();
    if (tid < 64) {
      float s = srow[tid] + srow[tid + 64];
#pragma unroll
      for (int off = 1; off < 64; off <<= 1) s += __shfl_xor(s, off);
      if (tid == 0) scal[1] = 1.f / s;
    }
    __syncthreads();

    // c_ctx + LSTM cell (thread = output dim d)
    {
      float cacc = 0.f;
      int cw = tid & 3, cd = tid >> 2;
#pragma unroll 8
      for (int qq = 0; qq < Q_N; ++qq) {
        int cc = cd ^ (qq & 7);
        cacc += srow[qq] * lds_q[qq * 256 + cc * 4 + cw];
      }
      float cctx = cacc * scal[1];
      float gi = grow[768 + tid]  + grow[1792 + tid] + bI;
      float gf = grow[1024 + tid] + grow[2048 + tid] + bF;
      float gg = grow[1280 + tid] + grow[2304 + tid] + bG;
      float go = grow[1536 + tid] + grow[2560 + tid] + bO;
      float cn = fsigmoid(gf) * cctx + fsigmoid(gi) * ftanh(gg);
      hout = fsigmoid(go) * ftanh(cn);
      __hip_atomic_store(&vstate[(size_t)b * 256 + tid], hout,
                         __ATOMIC_RELAXED, __HIP_MEMORY_SCOPE_AGENT);
    }
    signal_flag(&flagsB[g * 16 + m], (unsigned)(t + 1));
  }

  out[b * 256 + tid] = hout;
}

extern "C" void kernel_launch(void* const* d_in, const int* in_sizes, int n_in,
                              void* d_out, int out_size, void* d_ws, size_t ws_size,
                              hipStream_t stream) {
  const float* p   = (const float*)d_in[0];
  const float* q   = (const float*)d_in[1];
  const float* v0  = (const float*)d_in[2];
  const float* Wpu = (const float*)d_in[3];
  const float* Wqu = (const float*)d_in[4];
  const float* Wpv = (const float*)d_in[5];
  const float* Wih = (const float*)d_in[6];
  const float* Whh = (const float*)d_in[7];
  const float* bih = (const float*)d_in[8];
  const float* bhh = (const float*)d_in[9];
  float* out = (float*)d_out;

  char* ws = (char*)d_ws;
  unsigned short* Wh = (unsigned short*)(ws + 0x000000);   // 1,441,792 B
  unsigned short* Wm = (unsigned short*)(ws + 0x160000);   // 1,441,792 B
  unsigned short* Wl = (unsigned short*)(ws + 0x2C0000);   // 1,441,792 B
  float*    G      = (float*)(ws + 0x420000);              //   720,896 B
  float*    vstate = (float*)(ws + 0x4D0000);              //    65,536 B
  unsigned* flags  = (unsigned*)(ws + 0x4E0000);           //       512 B
  if (ws_size < 0x4E1000) return;

  const int prep_items = NCOL * 256 + B_N * 256 + 128;     // 737,408
  prep_kernel<<<(prep_items + 255) / 256, 256, 0, stream>>>(
      Wpu, Wqu, Wpv, Wih, Whh, v0, Wh, Wm, Wl, vstate, flags);

  const size_t smem_bytes = 40456 * sizeof(float);          // 161,824 <= 163,840
  hipFuncSetAttribute(reinterpret_cast<const void*>(pq_main),
                      hipFuncAttributeMaxDynamicSharedMemorySize, (int)smem_bytes);
  pq_main<<<64, NT, smem_bytes, stream>>>(p, q, bih, bhh, Wh, Wm, Wl,
                                          G, vstate, flags, flags + 64, out);
}

// Round 3
// 22327.271 us; speedup vs baseline: 1.1160x; 1.1160x over previous
//
#include <hip/hip_runtime.h>

#define T_LEN 1024
#define B_N   64
#define D_N   256
#define Q_N   128
#define WCOLS 2816      // Wcat: 256 w | 256 pu | 256 pv | 1024 gi | 1024 gh
#define GROW  1792      // exchanged row: 768 (w|pu|pv) + 1024 (gi+gh summed)
#define NT    256

typedef __attribute__((ext_vector_type(8))) short short8;
typedef __attribute__((ext_vector_type(4))) float floatx4;

#define MFMA16(A, B, C) __builtin_amdgcn_mfma_f32_16x16x32_bf16((A), (B), (C), 0, 0, 0)

__device__ __forceinline__ float fsigmoid(float x) { return 1.f / (1.f + __expf(-x)); }
__device__ __forceinline__ float ftanh(float x) {
  float ax = fabsf(x);
  float e = __expf(-2.f * ax);
  float r = (1.f - e) / (1.f + e);
  return (x < 0.f) ? -r : r;
}

// 3-term truncation split of A: x = h + m + l + eps, |eps| <~ 2^-24 |x|
struct Split3 { short8 h, m, l; };
__device__ __forceinline__ Split3 split8(const float* x) {
  union U { unsigned u[4]; short8 s; } H, M, L;
#pragma unroll
  for (int i = 0; i < 4; ++i) {
    float x0 = x[2 * i], x1 = x[2 * i + 1];
    unsigned h0 = __float_as_uint(x0) & 0xffff0000u;
    unsigned h1 = __float_as_uint(x1) & 0xffff0000u;
    float r0 = x0 - __uint_as_float(h0);
    float r1 = x1 - __uint_as_float(h1);
    unsigned m0 = __float_as_uint(r0) & 0xffff0000u;
    unsigned m1 = __float_as_uint(r1) & 0xffff0000u;
    float s0 = r0 - __uint_as_float(m0);
    float s1 = r1 - __uint_as_float(m1);
    H.u[i] = (h0 >> 16) | h1;
    M.u[i] = (m0 >> 16) | m1;
    L.u[i] = (__float_as_uint(s0) >> 16) | (__float_as_uint(s1) & 0xffff0000u);
  }
  Split3 r; r.h = H.s; r.m = M.s; r.l = L.s; return r;
}

// 5-product split MFMA: hh, hm, mh, mm, lh  (dropped hl ~2^-17 static weight-l)
__device__ __forceinline__ floatx4 mfma5(floatx4 acc, const Split3& A, short8 Bh, short8 Bm) {
  acc = MFMA16(A.l, Bh, acc);
  acc = MFMA16(A.m, Bm, acc);
  acc = MFMA16(A.m, Bh, acc);
  acc = MFMA16(A.h, Bm, acc);
  acc = MFMA16(A.h, Bh, acc);
  return acc;
}

// ---------------- prep: W -> 2-way bf16 split; vstate=v0; flags=0 ------------
__global__ void prep_kernel(const float* __restrict__ Wpu, const float* __restrict__ Wqu,
                            const float* __restrict__ Wpv, const float* __restrict__ Wih,
                            const float* __restrict__ Whh, const float* __restrict__ v0,
                            unsigned short* __restrict__ Wh, unsigned short* __restrict__ Wm,
                            float* __restrict__ vstate, unsigned* __restrict__ flags) {
  int idx = blockIdx.x * 256 + threadIdx.x;
  const int total = WCOLS * 256;                // 720896
  if (idx < total) {
    int n = idx >> 8, k = idx & 255;
    float w;
    if      (n < 256)  w = Wqu[k * 256 + n];            // w:  (v^T Wqu)_n
    else if (n < 512)  w = Wpu[k * 256 + (n - 256)];    // pu: (v^T Wpu^T... row-dot)
    else if (n < 768)  w = Wpv[k * 256 + (n - 512)];    // pv
    else if (n < 1792) w = Wih[(n - 768) * 256 + k];    // gi_j = sum_k v[k] Wih[j][k]
    else               w = Whh[(n - 1792) * 256 + k];   // gh_j = sum_k ut[k] Whh[j][k]
    unsigned hb = __float_as_uint(w) & 0xffff0000u;
    float r1 = w - __uint_as_float(hb);
    Wh[idx] = (unsigned short)(hb >> 16);
    Wm[idx] = (unsigned short)((__float_as_uint(r1) & 0xffff0000u) >> 16);
  } else if (idx < total + B_N * 256) {
    int i = idx - total;
    vstate[i] = v0[i];
  } else if (idx < total + B_N * 256 + 128) {
    flags[idx - total - B_N * 256] = 0u;
  }
}

// ---------------- group sync (16 members); bulk data uses PLAIN ops ----------
__device__ __forceinline__ void wait_flags(const unsigned* f, unsigned val) {
  if (threadIdx.x < 64) {
    const unsigned* fp = f + (threadIdx.x & 15);
    unsigned v;
    do {
      __builtin_amdgcn_s_sleep(1);
      v = __hip_atomic_load(fp, __ATOMIC_RELAXED, __HIP_MEMORY_SCOPE_AGENT);
    } while (__any((int)(v < val)));
  }
  if (threadIdx.x == 0) __builtin_amdgcn_fence(__ATOMIC_ACQUIRE, "agent"); // L1/L2 inv
  __syncthreads();
}
__device__ __forceinline__ void signal_flag(unsigned* f, unsigned val) {
  __syncthreads();                 // every wave drains its plain stores (vmcnt 0)
  if (threadIdx.x == 0) {
    __builtin_amdgcn_fence(__ATOMIC_RELEASE, "agent");   // L2 writeback to fabric
    __hip_atomic_store(f, val, __ATOMIC_RELAXED, __HIP_MEMORY_SCOPE_AGENT);
  }
}

// ---------------- main: 64 WGs x 256 thr; 4 groups x 16 WGs; b = g*16+m ------
__launch_bounds__(NT, 1)
__global__ void pq_main(const float* __restrict__ p, const float* __restrict__ q,
                        const float* __restrict__ v0,
                        const float* __restrict__ bih, const float* __restrict__ bhh,
                        const unsigned short* __restrict__ Wh,
                        const unsigned short* __restrict__ Wm,
                        float* G, float* vstate,
                        unsigned* flagsA, unsigned* flagsB,
                        float* __restrict__ out) {
  extern __shared__ float smem[];
  float* lds_q = smem;             // 128 x 256 fp32, xor-swizzled chunks (131072 B)
  float* warr  = smem + 32768;     // 256: w = v^T Wqu
  float* bpart = smem + 33024;     // 256
  float* spart = smem + 33280;     // 256
  float* srow  = smem + 33536;     // 128
  float* scal  = smem + 33664;     // beta, 1/r

  const int tid  = threadIdx.x;
  const int g    = blockIdx.x >> 4;
  const int m    = blockIdx.x & 15;
  const int b    = g * 16 + m;
  const int lane = tid & 63;
  const int widx = tid >> 6;             // wave 0..3
  const int gw   = m * 4 + widx;         // group-wave 0..63
  const int n1   = gw * 12;              // tile1: 12 cols of [w|pu|pv] (768 total)
  const int n2   = 768  + gw * 16;       // tile2: gi cols
  const int n3   = 1792 + gw * 16;       // tile3: gh cols (same j as tile2)
  const int row  = lane & 15;
  const int kb   = lane >> 4;

  // ---- one-time: stage my batch's q (fp32, swizzled), bias regs ----
  for (int i = 0; i < Q_N; ++i) {
    float val = q[((size_t)i * B_N + b) * D_N + tid];
    int cc = (tid >> 2) ^ (i & 7);
    lds_q[i * 256 + cc * 4 + (tid & 3)] = val;
  }
  const float bI = bih[tid]       + bhh[tid];
  const float bF = bih[256 + tid] + bhh[256 + tid];
  const float bG = bih[512 + tid] + bhh[512 + tid];
  const float bO = bih[768 + tid] + bhh[768 + tid];
  float vprev = v0[b * 256 + tid];
  __syncthreads();

  // ---- register-resident B fragments: 3 tiles x 2 splits x 8 k-steps ----
  short8 Bh1[8], Bm1[8], Bhg[8], Bmg[8], Bh2[8], Bm2[8];
#pragma unroll
  for (int ks = 0; ks < 8; ++ks) {
    int ko = ks * 32 + kb * 8;
    int c1 = (n1 + row) * 256 + ko;      // may read 4 cols past 767 -> harmless
    int c2 = (n2 + row) * 256 + ko;
    int c3 = (n3 + row) * 256 + ko;
    Bh1[ks] = *(const short8*)&Wh[c1];  Bm1[ks] = *(const short8*)&Wm[c1];
    Bhg[ks] = *(const short8*)&Wh[c2];  Bmg[ks] = *(const short8*)&Wm[c2];
    Bh2[ks] = *(const short8*)&Wh[c3];  Bm2[ks] = *(const short8*)&Wm[c3];
  }

  // ---- G2(t=0): gh tile from p[0] (plain cached loads) ----
  floatx4 acc2 = {0.f, 0.f, 0.f, 0.f};
  {
    const float* pb = p + ((size_t)0 * B_N + g * 16) * D_N;
#pragma unroll
    for (int ks = 0; ks < 8; ++ks) {
      float xa[8];
      const float* pr = pb + row * D_N + ks * 32 + kb * 8;
      *(float4*)&xa[0] = *(const float4*)pr;
      *(float4*)&xa[4] = *(const float4*)(pr + 4);
      Split3 A = split8(xa);
      acc2 = mfma5(acc2, A, Bh2[ks], Bm2[ks]);
    }
  }

  float hout = 0.f;

  for (int t = 0; t < T_LEN; ++t) {
    // ---- wait v_t visible; fabric-fresh after acquire fence ----
    wait_flags(flagsB + g * 16, (unsigned)t);

    // ---- G1: tiles 1 (w|pu|pv) and 2 (gi); A = v rows, plain global loads ----
    floatx4 acc1 = {0.f, 0.f, 0.f, 0.f}, accg = {0.f, 0.f, 0.f, 0.f};
    {
      const float* vb = vstate + (size_t)(g * 16) * 256;
#pragma unroll
      for (int ks = 0; ks < 8; ++ks) {
        float xa[8];
        const float* vr = vb + row * 256 + ks * 32 + kb * 8;
        *(float4*)&xa[0] = *(const float4*)vr;
        *(float4*)&xa[4] = *(const float4*)(vr + 4);
        Split3 A = split8(xa);
        acc1 = mfma5(acc1, A, Bh1[ks], Bm1[ks]);
        accg = mfma5(accg, A, Bhg[ks], Bmg[ks]);
      }
    }

    // ---- plain coalesced stores of my G slice (C/D: col=lane&15, row=quad*4+r)
    {
      int col = lane & 15, r0 = (lane >> 4) * 4;
#pragma unroll
      for (int r = 0; r < 4; ++r) {
        size_t brow = (size_t)(g * 16 + r0 + r) * GROW;
        if (col < 12) G[brow + n1 + col] = acc1[r];
        G[brow + 768 + gw * 16 + col] = accg[r] + acc2[r];   // gi + gh pre-summed
      }
    }
    signal_flag(&flagsA[g * 16 + m], (unsigned)(t + 1));

    // ---- next-step G2: off the critical path (others still in phase 1/2) ----
    floatx4 acc2n = {0.f, 0.f, 0.f, 0.f};
    if (t + 1 < T_LEN) {
      const float* pb = p + ((size_t)(t + 1) * B_N + g * 16) * D_N;
#pragma unroll
      for (int ks = 0; ks < 8; ++ks) {
        float xa[8];
        const float* pr = pb + row * D_N + ks * 32 + kb * 8;
        *(float4*)&xa[0] = *(const float4*)pr;
        *(float4*)&xa[4] = *(const float4*)(pr + 4);
        Split3 A = split8(xa);
        acc2n = mfma5(acc2n, A, Bh2[ks], Bm2[ks]);
      }
    }

    // ---- phase 2: my batch row (plain loads after acquire fence) ----
    wait_flags(flagsA + g * 16, (unsigned)(t + 1));
    const float* gr = G + (size_t)b * GROW;
    float wv_ = gr[tid];
    float pu  = gr[256 + tid];
    float pv  = gr[512 + tid];
    float g0  = gr[768 + tid];
    float g1  = gr[1024 + tid];
    float g2  = gr[1280 + tid];
    float g3  = gr[1536 + tid];
    float utd = p[((size_t)t * B_N + b) * D_N + tid];
    warr[tid]  = wv_;
    bpart[tid] = pu * utd + pv * vprev;
    __syncthreads();
    if (tid < 64) {
      float s = bpart[tid] + bpart[tid + 64] + bpart[tid + 128] + bpart[tid + 192];
#pragma unroll
      for (int off = 1; off < 64; off <<= 1) s += __shfl_xor(s, off);
      if (tid == 0) scal[0] = s;          // beta
    }
    {   // term1[q] = q[q,:].w  (swizzle-consistent fp32 dot)
      int qq = tid >> 1, half = tid & 1, k = qq & 7;
      const float4* qrow = (const float4*)&lds_q[qq * 256 + half * 128];
      const float4* wrow = (const float4*)&warr[half * 128];
      float acc = 0.f;
#pragma unroll 8
      for (int i = 0; i < 32; ++i) {
        float4 qv = qrow[i];
        float4 wv = wrow[i ^ k];
        acc += qv.x * wv.x + qv.y * wv.y + qv.z * wv.z + qv.w * wv.w;
      }
      spart[tid] = acc;
    }
    __syncthreads();
    if (tid < Q_N) srow[tid] = spart[2 * tid] + spart[2 * tid + 1] + scal[0];
    __syncthreads();
    if (tid < 64) {
      float s = srow[tid] + srow[tid + 64];
#pragma unroll
      for (int off = 1; off < 64; off <<= 1) s += __shfl_xor(s, off);
      if (tid == 0) scal[1] = 1.f / s;    // 1/r
    }
    __syncthreads();
    {   // c_ctx + LSTM cell (thread = output dim)
      float cacc = 0.f;
      int cw = tid & 3, cd = tid >> 2;
#pragma unroll 8
      for (int qq = 0; qq < Q_N; ++qq) {
        int cc = cd ^ (qq & 7);
        cacc += srow[qq] * lds_q[qq * 256 + cc * 4 + cw];
      }
      float cctx = cacc * scal[1];
      float cn = fsigmoid(g1 + bF) * cctx + fsigmoid(g0 + bI) * ftanh(g2 + bG);
      hout = fsigmoid(g3 + bO) * ftanh(cn);
      vstate[(size_t)b * 256 + tid] = hout;          // plain store
      vprev = hout;
    }
    signal_flag(&flagsB[g * 16 + m], (unsigned)(t + 1));
    acc2 = acc2n;
  }

  out[b * 256 + tid] = hout;
}

extern "C" void kernel_launch(void* const* d_in, const int* in_sizes, int n_in,
                              void* d_out, int out_size, void* d_ws, size_t ws_size,
                              hipStream_t stream) {
  const float* p   = (const float*)d_in[0];
  const float* q   = (const float*)d_in[1];
  const float* v0  = (const float*)d_in[2];
  const float* Wpu = (const float*)d_in[3];
  const float* Wqu = (const float*)d_in[4];
  const float* Wpv = (const float*)d_in[5];
  const float* Wih = (const float*)d_in[6];
  const float* Whh = (const float*)d_in[7];
  const float* bih = (const float*)d_in[8];
  const float* bhh = (const float*)d_in[9];
  float* out = (float*)d_out;

  char* ws = (char*)d_ws;
  unsigned short* Wh = (unsigned short*)(ws + 0x000000);   // 1,441,792 B
  unsigned short* Wm = (unsigned short*)(ws + 0x160000);   // 1,441,792 B
  float*    G      = (float*)(ws + 0x2C0000);              //   458,752 B
  float*    vstate = (float*)(ws + 0x330000);              //    65,536 B
  unsigned* flags  = (unsigned*)(ws + 0x340000);           //       512 B
  if (ws_size < 0x341000) return;

  const int prep_items = WCOLS * 256 + B_N * 256 + 128;    // 737,408
  prep_kernel<<<(prep_items + 255) / 256, 256, 0, stream>>>(
      Wpu, Wqu, Wpv, Wih, Whh, v0, Wh, Wm, vstate, flags);

  const size_t smem_bytes = 33672 * sizeof(float);          // 134,688 <= 163,840
  hipFuncSetAttribute(reinterpret_cast<const void*>(pq_main),
                      hipFuncAttributeMaxDynamicSharedMemorySize, (int)smem_bytes);
  pq_main<<<64, NT, smem_bytes, stream>>>(p, q, v0, bih, bhh, Wh, Wm,
                                          G, vstate, flags, flags + 64, out);
}